// Round 9
// baseline (286.423 us; speedup 1.0000x reference)
//
#include <hip/hip_runtime.h>
#include <hip/hip_bf16.h>

using f16 = _Float16;
typedef _Float16 f16x8 __attribute__((ext_vector_type(8)));
typedef _Float16 f16x4 __attribute__((ext_vector_type(4)));
typedef float f32x4 __attribute__((ext_vector_type(4)));

#define AS1 __attribute__((address_space(1)))
#define AS3 __attribute__((address_space(3)))

// Problem constants
constexpr int Bc = 4, Qc = 1024, Dc = 1024, Nh = 16, DHc = 64;
constexpr int BQ = Bc * Qc;      // 4096 rows of w
constexpr int NHEAD = Bc * Nh;   // 64 (b,n) heads
constexpr float ATT_SCALE = 0.125f;

// ---------------- f32 -> f16, 8 elems/thread ----------------
__global__ void k_f2h(const float* __restrict__ src, f16* __restrict__ dst) {
    long i8 = ((long)blockIdx.x * blockDim.x + threadIdx.x) * 8;
    float4 a = *(const float4*)&src[i8];
    float4 b = *(const float4*)&src[i8 + 4];
    f16x8 o = { (f16)a.x, (f16)a.y, (f16)a.z, (f16)a.w,
                (f16)b.x, (f16)b.y, (f16)b.z, (f16)b.w };
    *(f16x8*)&dst[i8] = o;
}

// ---------------- merged 4-way weight transpose: src[z][R][C] -> dst[z][C][R] f16 ----------------
struct Ptr4 { const float* p[4]; };
__global__ void k_transpose4(Ptr4 srcs, f16* __restrict__ dst) {
    __shared__ f16 tile[32][33];
    const float* src = srcs.p[blockIdx.z];
    f16* d = dst + (long)blockIdx.z * Dc * Dc;
    int c0 = blockIdx.x * 32, r0 = blockIdx.y * 32;
#pragma unroll
    for (int dy = 0; dy < 32; dy += 8) {
        int r = r0 + threadIdx.y + dy, c = c0 + threadIdx.x;
        tile[threadIdx.y + dy][threadIdx.x] = (f16)src[(long)r * Dc + c];
    }
    __syncthreads();
#pragma unroll
    for (int dy = 0; dy < 32; dy += 8) {
        int c = c0 + threadIdx.y + dy, r = r0 + threadIdx.x;
        d[(long)c * Dc + r] = tile[threadIdx.x][threadIdx.y + dy];
    }
}

// ---------------- fill Kt[h][j][64:128] = r_emb[j+1][n][:] (0 at j=1023) ----------------
__global__ void k_fill_remb(const float* __restrict__ remb, f16* __restrict__ Kt) {
    long gid = (long)blockIdx.x * blockDim.x + threadIdx.x;  // 64*1024*8
    int d8 = (int)(gid & 7) * 8;
    int j = (int)((gid >> 3) & 1023);
    int h = (int)(gid >> 13);
    int n = h & 15;
    f16x8 kv;
    if (j < 1023) {
        const float* rp = &remb[((long)(j + 1) * 16 + n) * 64 + d8];
        float4 r0 = *(const float4*)rp, r1 = *(const float4*)(rp + 4);
        kv[0] = (f16)r0.x; kv[1] = (f16)r0.y; kv[2] = (f16)r0.z; kv[3] = (f16)r0.w;
        kv[4] = (f16)r1.x; kv[5] = (f16)r1.y; kv[6] = (f16)r1.z; kv[7] = (f16)r1.w;
    } else {
        kv = f16x8{};
    }
    *(f16x8*)&Kt[(((long)h << 10) + j) * 128 + 64 + d8] = kv;
}

// ---------------- NT GEMM, global_load_lds staging, fused epilogues ----------------
// EPI: 0 = f16 row-major; 5 = fused QKV scatter (qtp/ktp/vtp, segment by n0>>10).
template <int BM, int BN, int BK, int WROWS, int WCOLS, int EPI>
__global__ __launch_bounds__(256) void k_gemm_nt(
    const f16* __restrict__ A, const f16* __restrict__ Bt, void* __restrict__ Cv,
    const float* __restrict__ aux, f16* __restrict__ qtp, f16* __restrict__ ktp,
    f16* __restrict__ vtp, int lda, int ldb, int ldc, int K)
{
    constexpr int TM = BM / (WROWS * 16);
    constexpr int TN = BN / (WCOLS * 16);
    __shared__ __align__(16) f16 sA[BM * BK];
    __shared__ __align__(16) f16 sB[BN * BK];

    const int tid = threadIdx.x;
    const int lane = tid & 63, wave = tid >> 6;
    const int wm = wave / WCOLS, wn = wave % WCOLS;
    const int m0 = blockIdx.y * BM, n0 = blockIdx.x * BN;

    f32x4 acc[TM][TN] = {};

    const int lrow = lane & 15;
    const int kq = (lane >> 4) * 8;
    const int srow = lane >> 2;            // 16 rows per 1KB chunk
    const int scol = (lane & 3) * 8;       // 4 lanes x 8 f16 per 64B row

    for (int k0 = 0; k0 < K; k0 += BK) {
        __syncthreads();
        constexpr int CHA = BM * BK / 512;   // 1KB chunks
#pragma unroll
        for (int ch = 0; ch < CHA / 4; ++ch) {
            int cc = ch * 4 + wave;
            __builtin_amdgcn_global_load_lds(
                (const AS1 void*)(const void*)&A[(long)(m0 + cc * 16 + srow) * lda + k0 + scol],
                (AS3 void*)(void*)&sA[cc * 512], 16, 0, 0);
        }
        constexpr int CHB = BN * BK / 512;
#pragma unroll
        for (int ch = 0; ch < CHB / 4; ++ch) {
            int cc = ch * 4 + wave;
            __builtin_amdgcn_global_load_lds(
                (const AS1 void*)(const void*)&Bt[(long)(n0 + cc * 16 + srow) * ldb + k0 + scol],
                (AS3 void*)(void*)&sB[cc * 512], 16, 0, 0);
        }
        __syncthreads();

        f16x8 af[TM], bfr[TN];
#pragma unroll
        for (int mi = 0; mi < TM; ++mi)
            af[mi] = *(const f16x8*)&sA[(wm * TM * 16 + mi * 16 + lrow) * BK + kq];
#pragma unroll
        for (int ni = 0; ni < TN; ++ni)
            bfr[ni] = *(const f16x8*)&sB[(wn * TN * 16 + ni * 16 + lrow) * BK + kq];
#pragma unroll
        for (int mi = 0; mi < TM; ++mi)
#pragma unroll
            for (int ni = 0; ni < TN; ++ni)
                acc[mi][ni] = __builtin_amdgcn_mfma_f32_16x16x32_f16(af[mi], bfr[ni], acc[mi][ni], 0, 0, 0);
    }

    const int crow = (lane >> 4) * 4;
    const int ccol = lane & 15;
#pragma unroll
    for (int mi = 0; mi < TM; ++mi)
#pragma unroll
        for (int ni = 0; ni < TN; ++ni)
#pragma unroll
            for (int r = 0; r < 4; ++r) {
                int gm = m0 + wm * TM * 16 + mi * 16 + crow + r;
                int gn = n0 + wn * TN * 16 + ni * 16 + ccol;
                float val = acc[mi][ni][r];
                if constexpr (EPI == 0) {
                    ((f16*)Cv)[(long)gm * ldc + gn] = (f16)val;
                } else {
                    // fused QKV scatter; segment uniform per block (BN=128 | 1024)
                    int seg = n0 >> 10;
                    int col = gn & 1023;
                    int n = col >> 6, d = col & 63, b = gm >> 10, i = gm & 1023;
                    long rowbase = ((((long)((b << 4) + n) << 10) + i) << 7);
                    if (seg == 0) {
                        qtp[rowbase + d] = (f16)(val + aux[col]);
                        qtp[rowbase + 64 + d] = (f16)val;
                    } else if (seg == 1) {
                        ktp[rowbase + d] = (f16)val;
                    } else {
                        vtp[(((long)(b << 10) + col) << 10) + i] = (f16)val;
                    }
                }
            }
}

// ---------------- fused flash attention v4: S^T layout, P in regs, XCD swizzle,
// register-prefetch double-buffer for K/V staging.
// 1D grid 512: head = ((bid>>3)&7)*8 + (bid&7)  -> same head => same bid%8 =>
// same XCD (round-robin heuristic); q_tile = bid>>6. All 8 q-blocks of a head
// co-resident on one XCD -> K/V re-reads hit that XCD's L2.
// Tripwire: WRITE_SIZE must stay 8192 KB (no scratch spill; ~212 live VGPR).
__global__ __launch_bounds__(256, 2) void k_flash(
    const f16* __restrict__ Qt, const f16* __restrict__ Kt,
    const f16* __restrict__ vT, const float* __restrict__ r_bias,
    f16* __restrict__ avp)
{
    constexpr int LDL = 136;
    __shared__ __align__(16) f16 sK[128 * LDL];
    __shared__ __align__(16) f16 sV[64 * LDL];
    __shared__ float sRB[128];

    const int tid = threadIdx.x, lane = tid & 63, wave = tid >> 6;
    const int bid = blockIdx.x;
    const int h = (((bid >> 3) & 7) << 3) | (bid & 7);
    const int i0 = (bid >> 6) * 128;
    const int b = h >> 4, n = h & 15;

    const f16* Qh = Qt + (long)h * Qc * 128;
    const f16* Kh = Kt + (long)h * Qc * 128;
    const f16* Vh = vT + (long)h * DHc * Qc;

    const int lrow = lane & 15;            // q (B-frag n) / row index
    const int quad = lane >> 4;
    const int kq = quad * 8;

    // Q fragments (B-operand of S^T): rows i0 + wave*32 + t*16 + lrow
    f16x8 aq[2][4];
#pragma unroll
    for (int t = 0; t < 2; ++t)
#pragma unroll
        for (int kc = 0; kc < 4; ++kc)
            aq[t][kc] = *(const f16x8*)&Qh[(long)(i0 + wave * 32 + t * 16 + lrow) * 128 + kc * 32 + kq];

    float m_i[2] = {-1e30f, -1e30f}, l_i[2] = {0.0f, 0.0f};
    f32x4 o_acc[2][4] = {};   // D[m=q][n=d]: row q=quad*4+reg, col d=lane&15

    // prefetch registers for next K/V tile (+ shifted r_bias element)
    f16x8 pk[8], pv[4];
    float prb;
    auto load_tile = [&](int j0) {
#pragma unroll
        for (int s = 0; s < 8; ++s) {
            int slot = s * 256 + tid, r = slot >> 4, c = (slot & 15) * 8;
            pk[s] = *(const f16x8*)&Kh[(long)(j0 + r) * 128 + c];
        }
#pragma unroll
        for (int s = 0; s < 4; ++s) {
            int slot = s * 256 + tid, r = slot >> 4, c = (slot & 15) * 8;
            pv[s] = *(const f16x8*)&Vh[(long)r * Qc + j0 + c];
        }
        int j = j0 + tid;
        prb = (tid < 128 && j < Qc - 1) ? r_bias[(j + 1) * Nh + n] : 0.0f;
    };

    load_tile(0);

    for (int j0 = 0; j0 < Qc; j0 += 128) {
        __syncthreads();   // prev iter's sK/sV/sRB reads complete
#pragma unroll
        for (int s = 0; s < 8; ++s) {
            int slot = s * 256 + tid, r = slot >> 4, c = (slot & 15) * 8;
            *(f16x8*)&sK[r * LDL + c] = pk[s];
        }
#pragma unroll
        for (int s = 0; s < 4; ++s) {
            int slot = s * 256 + tid, r = slot >> 4, c = (slot & 15) * 8;
            *(f16x8*)&sV[r * LDL + c] = pv[s];
        }
        if (tid < 128) sRB[tid] = prb;
        __syncthreads();

        if (j0 + 128 < Qc) load_tile(j0 + 128);   // global latency hidden behind compute

        // S^T: D[m=j][n=q], 128 j x 32 q per wave
        f32x4 s_acc[2][8] = {};
#pragma unroll
        for (int kc = 0; kc < 4; ++kc)
#pragma unroll
            for (int ni = 0; ni < 8; ++ni) {
                f16x8 bk = *(const f16x8*)&sK[(ni * 16 + lrow) * LDL + kc * 32 + kq];
                s_acc[0][ni] = __builtin_amdgcn_mfma_f32_16x16x32_f16(bk, aq[0][kc], s_acc[0][ni], 0, 0, 0);
                s_acc[1][ni] = __builtin_amdgcn_mfma_f32_16x16x32_f16(bk, aq[1][kc], s_acc[1][ni], 0, 0, 0);
            }

        // online softmax per q (= lane&15); j spread over regs (x4) and quads (x4)
        f16x4 pf[2][8];
        float alpha_t[2];
#pragma unroll
        for (int t = 0; t < 2; ++t) {
            float mx = -1e30f;
#pragma unroll
            for (int ni = 0; ni < 8; ++ni) {
                f32x4 rb4 = *(const f32x4*)&sRB[ni * 16 + quad * 4];
#pragma unroll
                for (int r = 0; r < 4; ++r) {
                    float v = (s_acc[t][ni][r] + rb4[r]) * ATT_SCALE;
                    s_acc[t][ni][r] = v;
                    mx = fmaxf(mx, v);
                }
            }
            mx = fmaxf(mx, __shfl_xor(mx, 16));
            mx = fmaxf(mx, __shfl_xor(mx, 32));
            float mn = fmaxf(m_i[t], mx);
            float alpha = __expf(m_i[t] - mn);
            float sm = 0.0f;
#pragma unroll
            for (int ni = 0; ni < 8; ++ni) {
                float e0 = __expf(s_acc[t][ni][0] - mn);
                float e1 = __expf(s_acc[t][ni][1] - mn);
                float e2 = __expf(s_acc[t][ni][2] - mn);
                float e3 = __expf(s_acc[t][ni][3] - mn);
                sm += (e0 + e1) + (e2 + e3);
                f16x4 pvv; pvv[0] = (f16)e0; pvv[1] = (f16)e1; pvv[2] = (f16)e2; pvv[3] = (f16)e3;
                pf[t][ni] = pvv;
            }
            sm += __shfl_xor(sm, 16);
            sm += __shfl_xor(sm, 32);
            l_i[t] = l_i[t] * alpha + sm;
            m_i[t] = mn;
            alpha_t[t] = alpha;
        }

        // rescale o_acc: broadcast alpha from lane (quad*4+r) of the q-group
#pragma unroll
        for (int t = 0; t < 2; ++t)
#pragma unroll
            for (int r = 0; r < 4; ++r) {
                float al = __shfl(alpha_t[t], quad * 4 + r);
#pragma unroll
                for (int dt = 0; dt < 4; ++dt) o_acc[t][dt][r] *= al;
            }

        // PV: D[m=q][n=d] += P[q][j] * V[j][d], K=16 chunks, P from registers
#pragma unroll
        for (int nj = 0; nj < 8; ++nj)
#pragma unroll
            for (int dt = 0; dt < 4; ++dt) {
                f16x4 bv = *(const f16x4*)&sV[(dt * 16 + lrow) * LDL + nj * 16 + quad * 4];
                o_acc[0][dt] = __builtin_amdgcn_mfma_f32_16x16x16f16(pf[0][nj], bv, o_acc[0][dt], 0, 0, 0);
                o_acc[1][dt] = __builtin_amdgcn_mfma_f32_16x16x16f16(pf[1][nj], bv, o_acc[1][dt], 0, 0, 0);
            }
    }

    // epilogue: avp[b][i][n*64+d] = O / l  (row q=quad*4+r, col d=lane&15)
#pragma unroll
    for (int t = 0; t < 2; ++t) {
        float linv = 1.0f / l_i[t];
#pragma unroll
        for (int r = 0; r < 4; ++r) {
            float li = __shfl(linv, quad * 4 + r);
            int i = i0 + wave * 32 + t * 16 + quad * 4 + r;
#pragma unroll
            for (int dt = 0; dt < 4; ++dt) {
                int d = dt * 16 + lrow;
                avp[((long)(b * Qc + i) << 10) + n * 64 + d] = (f16)(o_acc[t][dt][r] * li);
            }
        }
    }
}

// ---------------- residual + LayerNorm (w f32, ao f16; f32 output) ----------------
__global__ __launch_bounds__(256) void k_res_ln(const float* __restrict__ w, const f16* __restrict__ ao,
                                                const float* __restrict__ gamma, const float* __restrict__ beta,
                                                float* __restrict__ out) {
    const long base = (long)blockIdx.x * 1024;
    const int tid = threadIdx.x;
    float4 wv = *(const float4*)&w[base + tid * 4];
    f16x4 av = *(const f16x4*)&ao[base + tid * 4];
    float x[4] = { wv.x + (float)av[0], wv.y + (float)av[1],
                   wv.z + (float)av[2], wv.w + (float)av[3] };
    float s = x[0] + x[1] + x[2] + x[3];
    float s2 = x[0] * x[0] + x[1] * x[1] + x[2] * x[2] + x[3] * x[3];
#pragma unroll
    for (int off = 32; off; off >>= 1) { s += __shfl_down(s, off); s2 += __shfl_down(s2, off); }
    __shared__ float rs[4], rs2[4];
    if ((tid & 63) == 0) { rs[tid >> 6] = s; rs2[tid >> 6] = s2; }
    __syncthreads();
    s = rs[0] + rs[1] + rs[2] + rs[3];
    s2 = rs2[0] + rs2[1] + rs2[2] + rs2[3];
    float mu = s * (1.0f / 1024.0f);
    float var = s2 * (1.0f / 1024.0f) - mu * mu;
    float inv = rsqrtf(var + 1e-5f);
    float4 gv = *(const float4*)&gamma[tid * 4];
    float4 bv = *(const float4*)&beta[tid * 4];
    float4 o;
    o.x = (x[0] - mu) * inv * gv.x + bv.x;
    o.y = (x[1] - mu) * inv * gv.y + bv.y;
    o.z = (x[2] - mu) * inv * gv.z + bv.z;
    o.w = (x[3] - mu) * inv * gv.w + bv.w;
    *(float4*)&out[base + tid * 4] = o;
}

extern "C" void kernel_launch(void* const* d_in, const int* in_sizes, int n_in,
                              void* d_out, int out_size, void* d_ws, size_t ws_size,
                              hipStream_t stream) {
    const float* w_in   = (const float*)d_in[0];
    const float* r_emb  = (const float*)d_in[1];
    const float* r_wb   = (const float*)d_in[2];
    const float* r_bias = (const float*)d_in[3];
    const float* Wq     = (const float*)d_in[4];
    const float* Wk     = (const float*)d_in[5];
    const float* Wv     = (const float*)d_in[6];
    const float* Wo     = (const float*)d_in[7];
    const float* ln_g   = (const float*)d_in[8];
    const float* ln_b   = (const float*)d_in[9];
    float* out = (float*)d_out;

    // workspace carve-out (56MB fixed + aliases)
    char* p = (char*)d_ws;
    auto alloc = [&](size_t bytes) { char* r = p; p += (bytes + 255) & ~(size_t)255; return r; };
    f16* wh = (f16*)alloc((size_t)BQ * Dc * 2);          // 8 MB
    f16* WT = (f16*)alloc((size_t)4 * Dc * Dc * 2);      // 8 MB: WqT,WkT,WvT,WoT (contiguous!)
    f16* Qt = (f16*)alloc((size_t)NHEAD * Qc * 128 * 2); // 16 MB
    f16* Kt = (f16*)alloc((size_t)NHEAD * Qc * 128 * 2); // 16 MB
    f16* vT = (f16*)alloc((size_t)BQ * Dc * 2);          // 8 MB [b][dcol][i]
    f16* WoT = WT + (size_t)3 * Dc * Dc;
    // aliases (liveness-checked): wh dead after QKV GEMM; Qt dead after flash
    f16* avp = wh;                 // [b][i][1024] f16
    f16* ao  = (f16*)Qt;           // 8 MB f16

    // 1. f32->f16 of w (8/thread)
    k_f2h<<<(BQ * Dc) / (256 * 8), 256, 0, stream>>>(w_in, wh);

    // 2. transpose 4 weights in one dispatch (f32 -> f16); WqT/WkT/WvT contiguous = B of QKV GEMM
    Ptr4 srcs{{Wq, Wk, Wv, Wo}};
    k_transpose4<<<dim3(32, 32, 4), dim3(32, 8), 0, stream>>>(srcs, WT);

    // 3. rel-shifted r_emb -> Kt[...][64:128] (independent of GEMMs)
    k_fill_remb<<<(NHEAD * Qc * 8) / 256, 256, 0, stream>>>(r_emb, Kt);

    // 4. fused QKV projection: N=3072, scatter epilogue to Qt/Kt/vT (768 blocks)
    k_gemm_nt<128, 128, 32, 2, 2, 5><<<dim3(3 * Dc / 128, BQ / 128), 256, 0, stream>>>(
        wh, WT, nullptr, r_wb, Qt, Kt, vT, Dc, Dc, 0, Dc);

    // 5. fused attention (XCD-swizzled 1D grid 512)
    k_flash<<<512, 256, 0, stream>>>(Qt, Kt, vT, r_bias, avp);

    // 6. attn_out = avp @ Wo^T (64x128 tile -> 512 blocks; f16 out into aliased ao)
    k_gemm_nt<64, 128, 32, 2, 2, 0><<<dim3(Dc / 128, BQ / 64), 256, 0, stream>>>(
        avp, WoT, ao, nullptr, nullptr, nullptr, nullptr, Dc, Dc, Dc, Dc);

    // 7. out = LayerNorm(w + attn_out), fp32 output
    k_res_ln<<<BQ, 256, 0, stream>>>(w_in, ao, ln_g, ln_b, out);
}

// Round 10
// 233.480 us; speedup vs baseline: 1.2268x; 1.2268x over previous
//
#include <hip/hip_runtime.h>
#include <hip/hip_bf16.h>

using f16 = _Float16;
typedef _Float16 f16x8 __attribute__((ext_vector_type(8)));
typedef _Float16 f16x4 __attribute__((ext_vector_type(4)));
typedef float f32x4 __attribute__((ext_vector_type(4)));

#define AS1 __attribute__((address_space(1)))
#define AS3 __attribute__((address_space(3)))

// Problem constants
constexpr int Bc = 4, Qc = 1024, Dc = 1024, Nh = 16, DHc = 64;
constexpr int BQ = Bc * Qc;      // 4096 rows of w
constexpr int NHEAD = Bc * Nh;   // 64 (b,n) heads
constexpr float ATT_SCALE = 0.125f;

// ---------------- f32 -> f16, 8 elems/thread ----------------
__global__ void k_f2h(const float* __restrict__ src, f16* __restrict__ dst) {
    long i8 = ((long)blockIdx.x * blockDim.x + threadIdx.x) * 8;
    float4 a = *(const float4*)&src[i8];
    float4 b = *(const float4*)&src[i8 + 4];
    f16x8 o = { (f16)a.x, (f16)a.y, (f16)a.z, (f16)a.w,
                (f16)b.x, (f16)b.y, (f16)b.z, (f16)b.w };
    *(f16x8*)&dst[i8] = o;
}

// ---------------- merged 4-way weight transpose: src[z][R][C] -> dst[z][C][R] f16 ----------------
struct Ptr4 { const float* p[4]; };
__global__ void k_transpose4(Ptr4 srcs, f16* __restrict__ dst) {
    __shared__ f16 tile[32][33];
    const float* src = srcs.p[blockIdx.z];
    f16* d = dst + (long)blockIdx.z * Dc * Dc;
    int c0 = blockIdx.x * 32, r0 = blockIdx.y * 32;
#pragma unroll
    for (int dy = 0; dy < 32; dy += 8) {
        int r = r0 + threadIdx.y + dy, c = c0 + threadIdx.x;
        tile[threadIdx.y + dy][threadIdx.x] = (f16)src[(long)r * Dc + c];
    }
    __syncthreads();
#pragma unroll
    for (int dy = 0; dy < 32; dy += 8) {
        int c = c0 + threadIdx.y + dy, r = r0 + threadIdx.x;
        d[(long)c * Dc + r] = tile[threadIdx.x][threadIdx.y + dy];
    }
}

// ---------------- fill Kt[h][j][64:128] = r_emb[j+1][n][:] (0 at j=1023) ----------------
__global__ void k_fill_remb(const float* __restrict__ remb, f16* __restrict__ Kt) {
    long gid = (long)blockIdx.x * blockDim.x + threadIdx.x;  // 64*1024*8
    int d8 = (int)(gid & 7) * 8;
    int j = (int)((gid >> 3) & 1023);
    int h = (int)(gid >> 13);
    int n = h & 15;
    f16x8 kv;
    if (j < 1023) {
        const float* rp = &remb[((long)(j + 1) * 16 + n) * 64 + d8];
        float4 r0 = *(const float4*)rp, r1 = *(const float4*)(rp + 4);
        kv[0] = (f16)r0.x; kv[1] = (f16)r0.y; kv[2] = (f16)r0.z; kv[3] = (f16)r0.w;
        kv[4] = (f16)r1.x; kv[5] = (f16)r1.y; kv[6] = (f16)r1.z; kv[7] = (f16)r1.w;
    } else {
        kv = f16x8{};
    }
    *(f16x8*)&Kt[(((long)h << 10) + j) * 128 + 64 + d8] = kv;
}

// ---------------- NT GEMM, global_load_lds staging, fused epilogues ----------------
// EPI: 0 = f16 row-major; 5 = fused QKV scatter (qtp/ktp/vtp, segment by n0>>10).
template <int BM, int BN, int BK, int WROWS, int WCOLS, int EPI>
__global__ __launch_bounds__(256) void k_gemm_nt(
    const f16* __restrict__ A, const f16* __restrict__ Bt, void* __restrict__ Cv,
    const float* __restrict__ aux, f16* __restrict__ qtp, f16* __restrict__ ktp,
    f16* __restrict__ vtp, int lda, int ldb, int ldc, int K)
{
    constexpr int TM = BM / (WROWS * 16);
    constexpr int TN = BN / (WCOLS * 16);
    __shared__ __align__(16) f16 sA[BM * BK];
    __shared__ __align__(16) f16 sB[BN * BK];

    const int tid = threadIdx.x;
    const int lane = tid & 63, wave = tid >> 6;
    const int wm = wave / WCOLS, wn = wave % WCOLS;
    const int m0 = blockIdx.y * BM, n0 = blockIdx.x * BN;

    f32x4 acc[TM][TN] = {};

    const int lrow = lane & 15;
    const int kq = (lane >> 4) * 8;
    const int srow = lane >> 2;            // 16 rows per 1KB chunk
    const int scol = (lane & 3) * 8;       // 4 lanes x 8 f16 per 64B row

    for (int k0 = 0; k0 < K; k0 += BK) {
        __syncthreads();
        constexpr int CHA = BM * BK / 512;   // 1KB chunks
#pragma unroll
        for (int ch = 0; ch < CHA / 4; ++ch) {
            int cc = ch * 4 + wave;
            __builtin_amdgcn_global_load_lds(
                (const AS1 void*)(const void*)&A[(long)(m0 + cc * 16 + srow) * lda + k0 + scol],
                (AS3 void*)(void*)&sA[cc * 512], 16, 0, 0);
        }
        constexpr int CHB = BN * BK / 512;
#pragma unroll
        for (int ch = 0; ch < CHB / 4; ++ch) {
            int cc = ch * 4 + wave;
            __builtin_amdgcn_global_load_lds(
                (const AS1 void*)(const void*)&Bt[(long)(n0 + cc * 16 + srow) * ldb + k0 + scol],
                (AS3 void*)(void*)&sB[cc * 512], 16, 0, 0);
        }
        __syncthreads();

        f16x8 af[TM], bfr[TN];
#pragma unroll
        for (int mi = 0; mi < TM; ++mi)
            af[mi] = *(const f16x8*)&sA[(wm * TM * 16 + mi * 16 + lrow) * BK + kq];
#pragma unroll
        for (int ni = 0; ni < TN; ++ni)
            bfr[ni] = *(const f16x8*)&sB[(wn * TN * 16 + ni * 16 + lrow) * BK + kq];
#pragma unroll
        for (int mi = 0; mi < TM; ++mi)
#pragma unroll
            for (int ni = 0; ni < TN; ++ni)
                acc[mi][ni] = __builtin_amdgcn_mfma_f32_16x16x32_f16(af[mi], bfr[ni], acc[mi][ni], 0, 0, 0);
    }

    const int crow = (lane >> 4) * 4;
    const int ccol = lane & 15;
#pragma unroll
    for (int mi = 0; mi < TM; ++mi)
#pragma unroll
        for (int ni = 0; ni < TN; ++ni)
#pragma unroll
            for (int r = 0; r < 4; ++r) {
                int gm = m0 + wm * TM * 16 + mi * 16 + crow + r;
                int gn = n0 + wn * TN * 16 + ni * 16 + ccol;
                float val = acc[mi][ni][r];
                if constexpr (EPI == 0) {
                    ((f16*)Cv)[(long)gm * ldc + gn] = (f16)val;
                } else {
                    // fused QKV scatter; segment uniform per block (BN=128 | 1024)
                    int seg = n0 >> 10;
                    int col = gn & 1023;
                    int n = col >> 6, d = col & 63, b = gm >> 10, i = gm & 1023;
                    long rowbase = ((((long)((b << 4) + n) << 10) + i) << 7);
                    if (seg == 0) {
                        qtp[rowbase + d] = (f16)(val + aux[col]);
                        qtp[rowbase + 64 + d] = (f16)val;
                    } else if (seg == 1) {
                        ktp[rowbase + d] = (f16)val;
                    } else {
                        vtp[(((long)(b << 10) + col) << 10) + i] = (f16)val;
                    }
                }
            }
}

// ---------------- fused flash attention v5: S^T layout, P in regs, XCD swizzle,
// DIRECT LDS staging (register prefetch removed: rounds 5 & 9 both proved the
// ~200-reg live set spills — WRITE_SIZE tripwire fired both times).
// 1D grid 512: head = ((bid>>3)&7)*8 + (bid&7) -> same head => same bid%8 =>
// same XCD; q_tile = bid>>6. K/V re-reads across a head's 8 q-blocks hit L2.
__global__ __launch_bounds__(256, 2) void k_flash(
    const f16* __restrict__ Qt, const f16* __restrict__ Kt,
    const f16* __restrict__ vT, const float* __restrict__ r_bias,
    f16* __restrict__ avp)
{
    constexpr int LDL = 136;
    __shared__ __align__(16) f16 sK[128 * LDL];
    __shared__ __align__(16) f16 sV[64 * LDL];
    __shared__ float sRB[128];

    const int tid = threadIdx.x, lane = tid & 63, wave = tid >> 6;
    const int bid = blockIdx.x;
    const int h = (((bid >> 3) & 7) << 3) | (bid & 7);
    const int i0 = (bid >> 6) * 128;
    const int b = h >> 4, n = h & 15;

    const f16* Qh = Qt + (long)h * Qc * 128;
    const f16* Kh = Kt + (long)h * Qc * 128;
    const f16* Vh = vT + (long)h * DHc * Qc;

    const int lrow = lane & 15;            // q (B-frag n) / row index
    const int quad = lane >> 4;
    const int kq = quad * 8;

    // Q fragments (B-operand of S^T): rows i0 + wave*32 + t*16 + lrow
    f16x8 aq[2][4];
#pragma unroll
    for (int t = 0; t < 2; ++t)
#pragma unroll
        for (int kc = 0; kc < 4; ++kc)
            aq[t][kc] = *(const f16x8*)&Qh[(long)(i0 + wave * 32 + t * 16 + lrow) * 128 + kc * 32 + kq];

    float m_i[2] = {-1e30f, -1e30f}, l_i[2] = {0.0f, 0.0f};
    f32x4 o_acc[2][4] = {};   // D[m=q][n=d]: row q=quad*4+reg, col d=lane&15

    for (int j0 = 0; j0 < Qc; j0 += 128) {
        __syncthreads();   // prev iter's sK/sV/sRB reads complete
        for (int idx = tid; idx < 128 * 16; idx += 256) {
            int r = idx >> 4, c = (idx & 15) * 8;
            *(uint4*)&sK[r * LDL + c] = *(const uint4*)&Kh[(long)(j0 + r) * 128 + c];
        }
        for (int idx = tid; idx < 64 * 16; idx += 256) {
            int r = idx >> 4, c = (idx & 15) * 8;
            *(uint4*)&sV[r * LDL + c] = *(const uint4*)&Vh[(long)r * Qc + j0 + c];
        }
        if (tid < 128) {
            int j = j0 + tid;
            sRB[tid] = (j < Qc - 1) ? r_bias[(j + 1) * Nh + n] : 0.0f;
        }
        __syncthreads();

        // S^T: D[m=j][n=q], 128 j x 32 q per wave
        f32x4 s_acc[2][8] = {};
#pragma unroll
        for (int kc = 0; kc < 4; ++kc)
#pragma unroll
            for (int ni = 0; ni < 8; ++ni) {
                f16x8 bk = *(const f16x8*)&sK[(ni * 16 + lrow) * LDL + kc * 32 + kq];
                s_acc[0][ni] = __builtin_amdgcn_mfma_f32_16x16x32_f16(bk, aq[0][kc], s_acc[0][ni], 0, 0, 0);
                s_acc[1][ni] = __builtin_amdgcn_mfma_f32_16x16x32_f16(bk, aq[1][kc], s_acc[1][ni], 0, 0, 0);
            }

        // online softmax per q (= lane&15); j spread over regs (x4) and quads (x4)
        f16x4 pf[2][8];
        float alpha_t[2];
#pragma unroll
        for (int t = 0; t < 2; ++t) {
            float mx = -1e30f;
#pragma unroll
            for (int ni = 0; ni < 8; ++ni) {
                f32x4 rb4 = *(const f32x4*)&sRB[ni * 16 + quad * 4];
#pragma unroll
                for (int r = 0; r < 4; ++r) {
                    float v = (s_acc[t][ni][r] + rb4[r]) * ATT_SCALE;
                    s_acc[t][ni][r] = v;
                    mx = fmaxf(mx, v);
                }
            }
            mx = fmaxf(mx, __shfl_xor(mx, 16));
            mx = fmaxf(mx, __shfl_xor(mx, 32));
            float mn = fmaxf(m_i[t], mx);
            float alpha = __expf(m_i[t] - mn);
            float sm = 0.0f;
#pragma unroll
            for (int ni = 0; ni < 8; ++ni) {
                float e0 = __expf(s_acc[t][ni][0] - mn);
                float e1 = __expf(s_acc[t][ni][1] - mn);
                float e2 = __expf(s_acc[t][ni][2] - mn);
                float e3 = __expf(s_acc[t][ni][3] - mn);
                sm += (e0 + e1) + (e2 + e3);
                f16x4 pvv; pvv[0] = (f16)e0; pvv[1] = (f16)e1; pvv[2] = (f16)e2; pvv[3] = (f16)e3;
                pf[t][ni] = pvv;
            }
            sm += __shfl_xor(sm, 16);
            sm += __shfl_xor(sm, 32);
            l_i[t] = l_i[t] * alpha + sm;
            m_i[t] = mn;
            alpha_t[t] = alpha;
        }

        // rescale o_acc: broadcast alpha from lane (quad*4+r) of the q-group
#pragma unroll
        for (int t = 0; t < 2; ++t)
#pragma unroll
            for (int r = 0; r < 4; ++r) {
                float al = __shfl(alpha_t[t], quad * 4 + r);
#pragma unroll
                for (int dt = 0; dt < 4; ++dt) o_acc[t][dt][r] *= al;
            }

        // PV: D[m=q][n=d] += P[q][j] * V[j][d], K=16 chunks, P from registers
#pragma unroll
        for (int nj = 0; nj < 8; ++nj)
#pragma unroll
            for (int dt = 0; dt < 4; ++dt) {
                f16x4 bv = *(const f16x4*)&sV[(dt * 16 + lrow) * LDL + nj * 16 + quad * 4];
                o_acc[0][dt] = __builtin_amdgcn_mfma_f32_16x16x16f16(pf[0][nj], bv, o_acc[0][dt], 0, 0, 0);
                o_acc[1][dt] = __builtin_amdgcn_mfma_f32_16x16x16f16(pf[1][nj], bv, o_acc[1][dt], 0, 0, 0);
            }
    }

    // epilogue: avp[b][i][n*64+d] = O / l  (row q=quad*4+r, col d=lane&15)
#pragma unroll
    for (int t = 0; t < 2; ++t) {
        float linv = 1.0f / l_i[t];
#pragma unroll
        for (int r = 0; r < 4; ++r) {
            float li = __shfl(linv, quad * 4 + r);
            int i = i0 + wave * 32 + t * 16 + quad * 4 + r;
#pragma unroll
            for (int dt = 0; dt < 4; ++dt) {
                int d = dt * 16 + lrow;
                avp[((long)(b * Qc + i) << 10) + n * 64 + d] = (f16)(o_acc[t][dt][r] * li);
            }
        }
    }
}

// ---------------- residual + LayerNorm (w f32, ao f16; f32 output) ----------------
__global__ __launch_bounds__(256) void k_res_ln(const float* __restrict__ w, const f16* __restrict__ ao,
                                                const float* __restrict__ gamma, const float* __restrict__ beta,
                                                float* __restrict__ out) {
    const long base = (long)blockIdx.x * 1024;
    const int tid = threadIdx.x;
    float4 wv = *(const float4*)&w[base + tid * 4];
    f16x4 av = *(const f16x4*)&ao[base + tid * 4];
    float x[4] = { wv.x + (float)av[0], wv.y + (float)av[1],
                   wv.z + (float)av[2], wv.w + (float)av[3] };
    float s = x[0] + x[1] + x[2] + x[3];
    float s2 = x[0] * x[0] + x[1] * x[1] + x[2] * x[2] + x[3] * x[3];
#pragma unroll
    for (int off = 32; off; off >>= 1) { s += __shfl_down(s, off); s2 += __shfl_down(s2, off); }
    __shared__ float rs[4], rs2[4];
    if ((tid & 63) == 0) { rs[tid >> 6] = s; rs2[tid >> 6] = s2; }
    __syncthreads();
    s = rs[0] + rs[1] + rs[2] + rs[3];
    s2 = rs2[0] + rs2[1] + rs2[2] + rs2[3];
    float mu = s * (1.0f / 1024.0f);
    float var = s2 * (1.0f / 1024.0f) - mu * mu;
    float inv = rsqrtf(var + 1e-5f);
    float4 gv = *(const float4*)&gamma[tid * 4];
    float4 bv = *(const float4*)&beta[tid * 4];
    float4 o;
    o.x = (x[0] - mu) * inv * gv.x + bv.x;
    o.y = (x[1] - mu) * inv * gv.y + bv.y;
    o.z = (x[2] - mu) * inv * gv.z + bv.z;
    o.w = (x[3] - mu) * inv * gv.w + bv.w;
    *(float4*)&out[base + tid * 4] = o;
}

extern "C" void kernel_launch(void* const* d_in, const int* in_sizes, int n_in,
                              void* d_out, int out_size, void* d_ws, size_t ws_size,
                              hipStream_t stream) {
    const float* w_in   = (const float*)d_in[0];
    const float* r_emb  = (const float*)d_in[1];
    const float* r_wb   = (const float*)d_in[2];
    const float* r_bias = (const float*)d_in[3];
    const float* Wq     = (const float*)d_in[4];
    const float* Wk     = (const float*)d_in[5];
    const float* Wv     = (const float*)d_in[6];
    const float* Wo     = (const float*)d_in[7];
    const float* ln_g   = (const float*)d_in[8];
    const float* ln_b   = (const float*)d_in[9];
    float* out = (float*)d_out;

    // workspace carve-out (56MB fixed + aliases)
    char* p = (char*)d_ws;
    auto alloc = [&](size_t bytes) { char* r = p; p += (bytes + 255) & ~(size_t)255; return r; };
    f16* wh = (f16*)alloc((size_t)BQ * Dc * 2);          // 8 MB
    f16* WT = (f16*)alloc((size_t)4 * Dc * Dc * 2);      // 8 MB: WqT,WkT,WvT,WoT (contiguous!)
    f16* Qt = (f16*)alloc((size_t)NHEAD * Qc * 128 * 2); // 16 MB
    f16* Kt = (f16*)alloc((size_t)NHEAD * Qc * 128 * 2); // 16 MB
    f16* vT = (f16*)alloc((size_t)BQ * Dc * 2);          // 8 MB [b][dcol][i]
    f16* WoT = WT + (size_t)3 * Dc * Dc;
    // aliases (liveness-checked): wh dead after QKV GEMM; Qt dead after flash
    f16* avp = wh;                 // [b][i][1024] f16
    f16* ao  = (f16*)Qt;           // 8 MB f16

    // 1. f32->f16 of w (8/thread)
    k_f2h<<<(BQ * Dc) / (256 * 8), 256, 0, stream>>>(w_in, wh);

    // 2. transpose 4 weights in one dispatch (f32 -> f16); WqT/WkT/WvT contiguous = B of QKV GEMM
    Ptr4 srcs{{Wq, Wk, Wv, Wo}};
    k_transpose4<<<dim3(32, 32, 4), dim3(32, 8), 0, stream>>>(srcs, WT);

    // 3. rel-shifted r_emb -> Kt[...][64:128] (independent of GEMMs)
    k_fill_remb<<<(NHEAD * Qc * 8) / 256, 256, 0, stream>>>(r_emb, Kt);

    // 4. fused QKV projection: N=3072, scatter epilogue to Qt/Kt/vT (768 blocks)
    k_gemm_nt<128, 128, 32, 2, 2, 5><<<dim3(3 * Dc / 128, BQ / 128), 256, 0, stream>>>(
        wh, WT, nullptr, r_wb, Qt, Kt, vT, Dc, Dc, 0, Dc);

    // 5. fused attention (XCD-swizzled 1D grid 512)
    k_flash<<<512, 256, 0, stream>>>(Qt, Kt, vT, r_bias, avp);

    // 6. attn_out = avp @ Wo^T (64x128 tile -> 512 blocks; f16 out into aliased ao)
    k_gemm_nt<64, 128, 32, 2, 2, 0><<<dim3(Dc / 128, BQ / 64), 256, 0, stream>>>(
        avp, WoT, ao, nullptr, nullptr, nullptr, nullptr, Dc, Dc, Dc, Dc);

    // 7. out = LayerNorm(w + attn_out), fp32 output
    k_res_ln<<<BQ, 256, 0, stream>>>(w_in, ao, ln_g, ln_b, out);
}

// Round 11
// 223.846 us; speedup vs baseline: 1.2796x; 1.0430x over previous
//
#include <hip/hip_runtime.h>
#include <hip/hip_bf16.h>

using f16 = _Float16;
typedef _Float16 f16x8 __attribute__((ext_vector_type(8)));
typedef _Float16 f16x4 __attribute__((ext_vector_type(4)));
typedef float f32x4 __attribute__((ext_vector_type(4)));

#define AS1 __attribute__((address_space(1)))
#define AS3 __attribute__((address_space(3)))

// Problem constants
constexpr int Bc = 4, Qc = 1024, Dc = 1024, Nh = 16, DHc = 64;
constexpr int BQ = Bc * Qc;      // 4096 rows of w
constexpr int NHEAD = Bc * Nh;   // 64 (b,n) heads
constexpr float ATT_SCALE = 0.125f;

// ---------------- f32 -> f16, 8 elems/thread ----------------
__global__ void k_f2h(const float* __restrict__ src, f16* __restrict__ dst) {
    long i8 = ((long)blockIdx.x * blockDim.x + threadIdx.x) * 8;
    float4 a = *(const float4*)&src[i8];
    float4 b = *(const float4*)&src[i8 + 4];
    f16x8 o = { (f16)a.x, (f16)a.y, (f16)a.z, (f16)a.w,
                (f16)b.x, (f16)b.y, (f16)b.z, (f16)b.w };
    *(f16x8*)&dst[i8] = o;
}

// ---------------- merged 4-way weight transpose: src[z][R][C] -> dst[z][C][R] f16 ----------------
struct Ptr4 { const float* p[4]; };
__global__ void k_transpose4(Ptr4 srcs, f16* __restrict__ dst) {
    __shared__ f16 tile[32][33];
    const float* src = srcs.p[blockIdx.z];
    f16* d = dst + (long)blockIdx.z * Dc * Dc;
    int c0 = blockIdx.x * 32, r0 = blockIdx.y * 32;
#pragma unroll
    for (int dy = 0; dy < 32; dy += 8) {
        int r = r0 + threadIdx.y + dy, c = c0 + threadIdx.x;
        tile[threadIdx.y + dy][threadIdx.x] = (f16)src[(long)r * Dc + c];
    }
    __syncthreads();
#pragma unroll
    for (int dy = 0; dy < 32; dy += 8) {
        int c = c0 + threadIdx.y + dy, r = r0 + threadIdx.x;
        d[(long)c * Dc + r] = tile[threadIdx.x][threadIdx.y + dy];
    }
}

// ---------------- Ke[h][j][0:64] = r_emb[j+1][n][:] (0 at j=1023) ----------------
__global__ void k_fill_remb(const float* __restrict__ remb, f16* __restrict__ Ke) {
    long gid = (long)blockIdx.x * blockDim.x + threadIdx.x;  // 64*1024*8
    int d8 = (int)(gid & 7) * 8;
    int j = (int)((gid >> 3) & 1023);
    int h = (int)(gid >> 13);
    int n = h & 15;
    f16x8 kv;
    if (j < 1023) {
        const float* rp = &remb[((long)(j + 1) * 16 + n) * 64 + d8];
        float4 r0 = *(const float4*)rp, r1 = *(const float4*)(rp + 4);
        kv[0] = (f16)r0.x; kv[1] = (f16)r0.y; kv[2] = (f16)r0.z; kv[3] = (f16)r0.w;
        kv[4] = (f16)r1.x; kv[5] = (f16)r1.y; kv[6] = (f16)r1.z; kv[7] = (f16)r1.w;
    } else {
        kv = f16x8{};
    }
    *(f16x8*)&Ke[(((long)h << 10) + j) * 64 + d8] = kv;
}

// ---------------- NT GEMM, global_load_lds staging, fused epilogues ----------------
// EPI: 0 = f16 row-major; 5 = QKV: seg0/1 natural row-major to qtp/ktp, seg2 vT scatter.
template <int BM, int BN, int BK, int WROWS, int WCOLS, int EPI>
__global__ __launch_bounds__(256) void k_gemm_nt(
    const f16* __restrict__ A, const f16* __restrict__ Bt, void* __restrict__ Cv,
    f16* __restrict__ qtp, f16* __restrict__ ktp, f16* __restrict__ vtp,
    int lda, int ldb, int ldc, int K)
{
    constexpr int TM = BM / (WROWS * 16);
    constexpr int TN = BN / (WCOLS * 16);
    __shared__ __align__(16) f16 sA[BM * BK];
    __shared__ __align__(16) f16 sB[BN * BK];

    const int tid = threadIdx.x;
    const int lane = tid & 63, wave = tid >> 6;
    const int wm = wave / WCOLS, wn = wave % WCOLS;
    const int m0 = blockIdx.y * BM, n0 = blockIdx.x * BN;

    f32x4 acc[TM][TN] = {};

    const int lrow = lane & 15;
    const int kq = (lane >> 4) * 8;
    const int srow = lane >> 2;            // 16 rows per 1KB chunk
    const int scol = (lane & 3) * 8;       // 4 lanes x 8 f16 per 64B row

    for (int k0 = 0; k0 < K; k0 += BK) {
        __syncthreads();
        constexpr int CHA = BM * BK / 512;   // 1KB chunks
#pragma unroll
        for (int ch = 0; ch < CHA / 4; ++ch) {
            int cc = ch * 4 + wave;
            __builtin_amdgcn_global_load_lds(
                (const AS1 void*)(const void*)&A[(long)(m0 + cc * 16 + srow) * lda + k0 + scol],
                (AS3 void*)(void*)&sA[cc * 512], 16, 0, 0);
        }
        constexpr int CHB = BN * BK / 512;
#pragma unroll
        for (int ch = 0; ch < CHB / 4; ++ch) {
            int cc = ch * 4 + wave;
            __builtin_amdgcn_global_load_lds(
                (const AS1 void*)(const void*)&Bt[(long)(n0 + cc * 16 + srow) * ldb + k0 + scol],
                (AS3 void*)(void*)&sB[cc * 512], 16, 0, 0);
        }
        __syncthreads();

        f16x8 af[TM], bfr[TN];
#pragma unroll
        for (int mi = 0; mi < TM; ++mi)
            af[mi] = *(const f16x8*)&sA[(wm * TM * 16 + mi * 16 + lrow) * BK + kq];
#pragma unroll
        for (int ni = 0; ni < TN; ++ni)
            bfr[ni] = *(const f16x8*)&sB[(wn * TN * 16 + ni * 16 + lrow) * BK + kq];
#pragma unroll
        for (int mi = 0; mi < TM; ++mi)
#pragma unroll
            for (int ni = 0; ni < TN; ++ni)
                acc[mi][ni] = __builtin_amdgcn_mfma_f32_16x16x32_f16(af[mi], bfr[ni], acc[mi][ni], 0, 0, 0);
    }

    const int crow = (lane >> 4) * 4;
    const int ccol = lane & 15;
#pragma unroll
    for (int mi = 0; mi < TM; ++mi)
#pragma unroll
        for (int ni = 0; ni < TN; ++ni)
#pragma unroll
            for (int r = 0; r < 4; ++r) {
                int gm = m0 + wm * TM * 16 + mi * 16 + crow + r;
                int gn = n0 + wn * TN * 16 + ni * 16 + ccol;
                float val = acc[mi][ni][r];
                if constexpr (EPI == 0) {
                    ((f16*)Cv)[(long)gm * ldc + gn] = (f16)val;
                } else {
                    int seg = n0 >> 10;       // block-uniform (BN=128 | 1024)
                    int col = gn & 1023;
                    if (seg == 0) {
                        qtp[(long)gm * 1024 + col] = (f16)val;
                    } else if (seg == 1) {
                        ktp[(long)gm * 1024 + col] = (f16)val;
                    } else {
                        int b = gm >> 10, i = gm & 1023;
                        vtp[(((long)(b << 10) + col) << 10) + i] = (f16)val;
                    }
                }
            }
}

// ---------------- fused flash attention v6: natural-layout Q/K + Ke, S^T, P in regs,
// XCD swizzle, direct LDS staging.
// Q frags: loaded once from qh[b*Q+i][n*64+d]; aq[0..1] = q + rwb (reg-built),
// aq[2..3] = q  — Qt buffer eliminated. sK halves staged from kh (natural) and
// Ke (rel-shifted r_emb) — Kt buffer eliminated.
// 1D grid 512: head = ((bid>>3)&7)*8 + (bid&7) -> same head => same XCD.
// Tripwires: WRITE_SIZE == 8192 KB (no spill); absmax == 0.03125 (layout ok).
__global__ __launch_bounds__(256, 2) void k_flash(
    const f16* __restrict__ qh, const f16* __restrict__ kh,
    const f16* __restrict__ Ke, const f16* __restrict__ vT,
    const float* __restrict__ rwb, const float* __restrict__ r_bias,
    f16* __restrict__ avp)
{
    constexpr int LDL = 136;
    __shared__ __align__(16) f16 sK[128 * LDL];   // cols 0..63 = k, 64..127 = remb
    __shared__ __align__(16) f16 sV[64 * LDL];
    __shared__ float sRB[128];

    const int tid = threadIdx.x, lane = tid & 63, wave = tid >> 6;
    const int bid = blockIdx.x;
    const int h = (((bid >> 3) & 7) << 3) | (bid & 7);
    const int i0 = (bid >> 6) * 128;
    const int b = h >> 4, n = h & 15;

    const f16* Vh = vT + (long)h * DHc * Qc;

    const int lrow = lane & 15;            // q (B-frag n) / row index
    const int quad = lane >> 4;

    // r_w_bias fragments (f32 -> f16), d ranges [quad*8, quad*8+8) and +32
    f16x8 rw0, rw1;
#pragma unroll
    for (int e = 0; e < 8; ++e) {
        rw0[e] = (f16)rwb[n * 64 + quad * 8 + e];
        rw1[e] = (f16)rwb[n * 64 + 32 + quad * 8 + e];
    }

    // Q fragments (B-operand of S^T): q loaded once, both halves built in regs
    f16x8 aq[2][4];
#pragma unroll
    for (int t = 0; t < 2; ++t) {
        long rix = (long)(b * Qc + i0 + wave * 32 + t * 16 + lrow) * 1024 + n * 64;
        f16x8 q0 = *(const f16x8*)&qh[rix + quad * 8];
        f16x8 q1 = *(const f16x8*)&qh[rix + 32 + quad * 8];
        aq[t][0] = q0 + rw0;   // k-dim [0,32):  q + r_w_bias
        aq[t][1] = q1 + rw1;   // k-dim [32,64)
        aq[t][2] = q0;         // k-dim [64,96):  q (dot r_emb half)
        aq[t][3] = q1;         // k-dim [96,128)
    }

    float m_i[2] = {-1e30f, -1e30f}, l_i[2] = {0.0f, 0.0f};
    f32x4 o_acc[2][4] = {};   // D[m=q][n=d]: row q=quad*4+reg, col d=lane&15

    for (int j0 = 0; j0 < Qc; j0 += 128) {
        __syncthreads();   // prev iter's sK/sV/sRB reads complete
        for (int idx = tid; idx < 1024; idx += 256) {
            int r = idx >> 3, c = (idx & 7) * 8;
            *(uint4*)&sK[r * LDL + c] =
                *(const uint4*)&kh[(long)(b * Qc + j0 + r) * 1024 + n * 64 + c];
            *(uint4*)&sK[r * LDL + 64 + c] =
                *(const uint4*)&Ke[((long)h * Qc + j0 + r) * 64 + c];
        }
        for (int idx = tid; idx < 64 * 16; idx += 256) {
            int r = idx >> 4, c = (idx & 15) * 8;
            *(uint4*)&sV[r * LDL + c] = *(const uint4*)&Vh[(long)r * Qc + j0 + c];
        }
        if (tid < 128) {
            int j = j0 + tid;
            sRB[tid] = (j < Qc - 1) ? r_bias[(j + 1) * Nh + n] : 0.0f;
        }
        __syncthreads();

        // S^T: D[m=j][n=q], 128 j x 32 q per wave
        f32x4 s_acc[2][8] = {};
#pragma unroll
        for (int kc = 0; kc < 4; ++kc)
#pragma unroll
            for (int ni = 0; ni < 8; ++ni) {
                f16x8 bk = *(const f16x8*)&sK[(ni * 16 + lrow) * LDL + kc * 32 + quad * 8];
                s_acc[0][ni] = __builtin_amdgcn_mfma_f32_16x16x32_f16(bk, aq[0][kc], s_acc[0][ni], 0, 0, 0);
                s_acc[1][ni] = __builtin_amdgcn_mfma_f32_16x16x32_f16(bk, aq[1][kc], s_acc[1][ni], 0, 0, 0);
            }

        // online softmax per q (= lane&15); j spread over regs (x4) and quads (x4)
        f16x4 pf[2][8];
        float alpha_t[2];
#pragma unroll
        for (int t = 0; t < 2; ++t) {
            float mx = -1e30f;
#pragma unroll
            for (int ni = 0; ni < 8; ++ni) {
                f32x4 rb4 = *(const f32x4*)&sRB[ni * 16 + quad * 4];
#pragma unroll
                for (int r = 0; r < 4; ++r) {
                    float v = (s_acc[t][ni][r] + rb4[r]) * ATT_SCALE;
                    s_acc[t][ni][r] = v;
                    mx = fmaxf(mx, v);
                }
            }
            mx = fmaxf(mx, __shfl_xor(mx, 16));
            mx = fmaxf(mx, __shfl_xor(mx, 32));
            float mn = fmaxf(m_i[t], mx);
            float alpha = __expf(m_i[t] - mn);
            float sm = 0.0f;
#pragma unroll
            for (int ni = 0; ni < 8; ++ni) {
                float e0 = __expf(s_acc[t][ni][0] - mn);
                float e1 = __expf(s_acc[t][ni][1] - mn);
                float e2 = __expf(s_acc[t][ni][2] - mn);
                float e3 = __expf(s_acc[t][ni][3] - mn);
                sm += (e0 + e1) + (e2 + e3);
                f16x4 pvv; pvv[0] = (f16)e0; pvv[1] = (f16)e1; pvv[2] = (f16)e2; pvv[3] = (f16)e3;
                pf[t][ni] = pvv;
            }
            sm += __shfl_xor(sm, 16);
            sm += __shfl_xor(sm, 32);
            l_i[t] = l_i[t] * alpha + sm;
            m_i[t] = mn;
            alpha_t[t] = alpha;
        }

        // rescale o_acc: broadcast alpha from lane (quad*4+r) of the q-group
#pragma unroll
        for (int t = 0; t < 2; ++t)
#pragma unroll
            for (int r = 0; r < 4; ++r) {
                float al = __shfl(alpha_t[t], quad * 4 + r);
#pragma unroll
                for (int dt = 0; dt < 4; ++dt) o_acc[t][dt][r] *= al;
            }

        // PV: D[m=q][n=d] += P[q][j] * V[j][d], K=16 chunks, P from registers
#pragma unroll
        for (int nj = 0; nj < 8; ++nj)
#pragma unroll
            for (int dt = 0; dt < 4; ++dt) {
                f16x4 bv = *(const f16x4*)&sV[(dt * 16 + lrow) * LDL + nj * 16 + quad * 4];
                o_acc[0][dt] = __builtin_amdgcn_mfma_f32_16x16x16f16(pf[0][nj], bv, o_acc[0][dt], 0, 0, 0);
                o_acc[1][dt] = __builtin_amdgcn_mfma_f32_16x16x16f16(pf[1][nj], bv, o_acc[1][dt], 0, 0, 0);
            }
    }

    // epilogue: avp[b][i][n*64+d] = O / l  (row q=quad*4+r, col d=lane&15)
#pragma unroll
    for (int t = 0; t < 2; ++t) {
        float linv = 1.0f / l_i[t];
#pragma unroll
        for (int r = 0; r < 4; ++r) {
            float li = __shfl(linv, quad * 4 + r);
            int i = i0 + wave * 32 + t * 16 + quad * 4 + r;
#pragma unroll
            for (int dt = 0; dt < 4; ++dt) {
                int d = dt * 16 + lrow;
                avp[((long)(b * Qc + i) << 10) + n * 64 + d] = (f16)(o_acc[t][dt][r] * li);
            }
        }
    }
}

// ---------------- residual + LayerNorm (w f32, ao f16; f32 output) ----------------
__global__ __launch_bounds__(256) void k_res_ln(const float* __restrict__ w, const f16* __restrict__ ao,
                                                const float* __restrict__ gamma, const float* __restrict__ beta,
                                                float* __restrict__ out) {
    const long base = (long)blockIdx.x * 1024;
    const int tid = threadIdx.x;
    float4 wv = *(const float4*)&w[base + tid * 4];
    f16x4 av = *(const f16x4*)&ao[base + tid * 4];
    float x[4] = { wv.x + (float)av[0], wv.y + (float)av[1],
                   wv.z + (float)av[2], wv.w + (float)av[3] };
    float s = x[0] + x[1] + x[2] + x[3];
    float s2 = x[0] * x[0] + x[1] * x[1] + x[2] * x[2] + x[3] * x[3];
#pragma unroll
    for (int off = 32; off; off >>= 1) { s += __shfl_down(s, off); s2 += __shfl_down(s2, off); }
    __shared__ float rs[4], rs2[4];
    if ((tid & 63) == 0) { rs[tid >> 6] = s; rs2[tid >> 6] = s2; }
    __syncthreads();
    s = rs[0] + rs[1] + rs[2] + rs[3];
    s2 = rs2[0] + rs2[1] + rs2[2] + rs2[3];
    float mu = s * (1.0f / 1024.0f);
    float var = s2 * (1.0f / 1024.0f) - mu * mu;
    float inv = rsqrtf(var + 1e-5f);
    float4 gv = *(const float4*)&gamma[tid * 4];
    float4 bv = *(const float4*)&beta[tid * 4];
    float4 o;
    o.x = (x[0] - mu) * inv * gv.x + bv.x;
    o.y = (x[1] - mu) * inv * gv.y + bv.y;
    o.z = (x[2] - mu) * inv * gv.z + bv.z;
    o.w = (x[3] - mu) * inv * gv.w + bv.w;
    *(float4*)&out[base + tid * 4] = o;
}

extern "C" void kernel_launch(void* const* d_in, const int* in_sizes, int n_in,
                              void* d_out, int out_size, void* d_ws, size_t ws_size,
                              hipStream_t stream) {
    const float* w_in   = (const float*)d_in[0];
    const float* r_emb  = (const float*)d_in[1];
    const float* r_wb   = (const float*)d_in[2];
    const float* r_bias = (const float*)d_in[3];
    const float* Wq     = (const float*)d_in[4];
    const float* Wk     = (const float*)d_in[5];
    const float* Wv     = (const float*)d_in[6];
    const float* Wo     = (const float*)d_in[7];
    const float* ln_g   = (const float*)d_in[8];
    const float* ln_b   = (const float*)d_in[9];
    float* out = (float*)d_out;

    // workspace carve-out (48MB fixed + aliases)
    char* p = (char*)d_ws;
    auto alloc = [&](size_t bytes) { char* r = p; p += (bytes + 255) & ~(size_t)255; return r; };
    f16* wh = (f16*)alloc((size_t)BQ * Dc * 2);          // 8 MB
    f16* WT = (f16*)alloc((size_t)4 * Dc * Dc * 2);      // 8 MB: WqT,WkT,WvT,WoT (contiguous)
    f16* qh = (f16*)alloc((size_t)BQ * Dc * 2);          // 8 MB [b*Q+i][n*64+d]
    f16* kh = (f16*)alloc((size_t)BQ * Dc * 2);          // 8 MB [b*Q+j][n*64+d]
    f16* Ke = (f16*)alloc((size_t)NHEAD * Qc * DHc * 2); // 8 MB [h][j][64] rel-shifted r_emb
    f16* vT = (f16*)alloc((size_t)BQ * Dc * 2);          // 8 MB [b][dcol][j]
    f16* WoT = WT + (size_t)3 * Dc * Dc;
    // aliases (liveness-checked): wh dead after QKV GEMM; Ke dead after flash
    f16* avp = wh;                 // [b][i][1024] f16
    f16* ao  = Ke;                 // 8 MB f16

    // 1. f32->f16 of w (8/thread)
    k_f2h<<<(BQ * Dc) / (256 * 8), 256, 0, stream>>>(w_in, wh);

    // 2. transpose 4 weights in one dispatch (f32 -> f16)
    Ptr4 srcs{{Wq, Wk, Wv, Wo}};
    k_transpose4<<<dim3(32, 32, 4), dim3(32, 8), 0, stream>>>(srcs, WT);

    // 3. rel-shifted r_emb -> Ke (independent of GEMMs)
    k_fill_remb<<<(NHEAD * Qc * 8) / 256, 256, 0, stream>>>(r_emb, Ke);

    // 4. fused QKV projection: N=3072; seg0/1 natural row-major, seg2 vT scatter
    k_gemm_nt<128, 128, 32, 2, 2, 5><<<dim3(3 * Dc / 128, BQ / 128), 256, 0, stream>>>(
        wh, WT, nullptr, qh, kh, vT, Dc, Dc, 0, Dc);

    // 5. fused attention (XCD-swizzled 1D grid 512); rwb folded into Q frags
    k_flash<<<512, 256, 0, stream>>>(qh, kh, Ke, vT, r_wb, r_bias, avp);

    // 6. attn_out = avp @ Wo^T (64x128 tile -> 512 blocks; f16 out into aliased ao)
    k_gemm_nt<64, 128, 32, 2, 2, 0><<<dim3(Dc / 128, BQ / 64), 256, 0, stream>>>(
        avp, WoT, ao, nullptr, nullptr, nullptr, Dc, Dc, Dc, Dc);

    // 7. out = LayerNorm(w + attn_out), fp32 output
    k_res_ln<<<BQ, 256, 0, stream>>>(w_in, ao, ln_g, ln_b, out);
}